// Round 8
// baseline (13.225 us; speedup 1.0000x reference)
//
#include <hip/hip_runtime.h>

#define NCL_EPS 1e-12f

// Single kernel node. 64 blocks x 1024 threads; each quarter-wave (16 lanes)
// owns one row: 2x float4 from x, 2x float4 from gathered center row (all
// issued breadth-first), 4-step butterfly reduce of {xx,cc,xc} within the
// 16-lane group. 64 rows/block. Wave 0 parallel-reduces the 64 group losses
// -> block partial. Two-level ticket tree (8 groups x 8 blocks): level-1
// fetch_add per group, sub-winner takes level-2 ticket; the 8th sub-winner
// has transitive proof all 64 partials are released, reduces them in fixed
// order, writes the mean, resets the level-2 counter. Deterministic.
__global__ __launch_bounds__(1024) void ncl_tree_kernel(
    const float* __restrict__ x,
    const int* __restrict__ labels,
    const float* __restrict__ centers,
    float* __restrict__ partials,        // [nblocks] @ d_ws+0
    unsigned int* __restrict__ c1,       // 8 counters, stride 16 uints (64B)
    unsigned int* __restrict__ c2,       // 1 counter
    float* __restrict__ out,
    int batch, int nblocks)
{
    const int tid = threadIdx.x;
    const int bid = blockIdx.x;
    const int grp = tid >> 4;     // group-in-block 0..63
    const int ql  = tid & 15;     // lane within 16-lane group

    const int row0 = bid * 64 + grp;
    const int row  = min(row0, batch - 1);
    const float vr = (row0 < batch) ? 1.0f : 0.0f;

    // Breadth-first: label, then 4 vector loads all in flight.
    const int lbl = labels[row];
    const float4* px = reinterpret_cast<const float4*>(x + (size_t)row * 128);
    const float4* pc = reinterpret_cast<const float4*>(centers + (size_t)lbl * 128);
    const float4 xv0 = px[ql];
    const float4 xv1 = px[ql + 16];
    const float4 cv0 = pc[ql];
    const float4 cv1 = pc[ql + 16];

    float xx = xv0.x * xv0.x + xv0.y * xv0.y + xv0.z * xv0.z + xv0.w * xv0.w
             + xv1.x * xv1.x + xv1.y * xv1.y + xv1.z * xv1.z + xv1.w * xv1.w;
    float cc = cv0.x * cv0.x + cv0.y * cv0.y + cv0.z * cv0.z + cv0.w * cv0.w
             + cv1.x * cv1.x + cv1.y * cv1.y + cv1.z * cv1.z + cv1.w * cv1.w;
    float xc = xv0.x * cv0.x + xv0.y * cv0.y + xv0.z * cv0.z + xv0.w * cv0.w
             + xv1.x * cv1.x + xv1.y * cv1.y + xv1.z * cv1.z + xv1.w * cv1.w;

    #pragma unroll
    for (int off = 8; off >= 1; off >>= 1) {
        xx += __shfl_xor(xx, off, 64);
        cc += __shfl_xor(cc, off, 64);
        xc += __shfl_xor(xc, off, 64);
    }

    __shared__ float sm[64];
    __shared__ unsigned int s_go;
    if (ql == 0) {
        const float nx = fmaxf(sqrtf(xx), NCL_EPS);
        const float nc = fmaxf(sqrtf(cc), NCL_EPS);
        sm[grp] = vr * (1.0f - xc / (nx * nc));
    }
    __syncthreads();

    // wave 0: parallel block reduce of 64 group losses
    if (tid < 64) {
        float s = sm[tid];
        #pragma unroll
        for (int off = 32; off >= 1; off >>= 1) s += __shfl_xor(s, off, 64);
        if (tid == 0) {
            __hip_atomic_store(&partials[bid], s,
                               __ATOMIC_RELAXED, __HIP_MEMORY_SCOPE_AGENT);
            const int g = bid & 7;
            const unsigned int old1 = __hip_atomic_fetch_add(
                &c1[g * 16], 1u, __ATOMIC_ACQ_REL, __HIP_MEMORY_SCOPE_AGENT);
            unsigned int fin = 0u;
            if (old1 == 7u || old1 == 0xAAAAAAAAu + 7u) {
                // group sub-winner: reset own counter, take level-2 ticket
                __hip_atomic_store(&c1[g * 16], 0u,
                                   __ATOMIC_RELAXED, __HIP_MEMORY_SCOPE_AGENT);
                const unsigned int old2 = __hip_atomic_fetch_add(
                    c2, 1u, __ATOMIC_ACQ_REL, __HIP_MEMORY_SCOPE_AGENT);
                fin = (old2 == 7u || old2 == 0xAAAAAAAAu + 7u) ? 1u : 0u;
            }
            s_go = fin;
        }
    }
    __syncthreads();

    if (s_go && tid < 64) {
        float s = (tid < nblocks)
            ? __hip_atomic_load(&partials[tid],
                                __ATOMIC_RELAXED, __HIP_MEMORY_SCOPE_AGENT)
            : 0.0f;
        #pragma unroll
        for (int off = 32; off >= 1; off >>= 1) s += __shfl_xor(s, off, 64);
        if (tid == 0) {
            out[0] = s / (float)batch;
            __hip_atomic_store(c2, 0u,
                               __ATOMIC_RELAXED, __HIP_MEMORY_SCOPE_AGENT);
        }
    }
}

extern "C" void kernel_launch(void* const* d_in, const int* in_sizes, int n_in,
                              void* d_out, int out_size, void* d_ws, size_t ws_size,
                              hipStream_t stream) {
    const float* x       = (const float*)d_in[0];
    const int*   labels  = (const int*)d_in[1];
    const float* centers = (const float*)d_in[2];
    float* out = (float*)d_out;

    const int batch   = in_sizes[1];          // 4096
    const int nblocks = (batch + 63) / 64;    // 64

    float*        partials = (float*)d_ws;
    unsigned int* c1       = (unsigned int*)((char*)d_ws + 1024);  // 8 x 64B
    unsigned int* c2       = (unsigned int*)((char*)d_ws + 2048);

    ncl_tree_kernel<<<nblocks, 1024, 0, stream>>>(
        x, labels, centers, partials, c1, c2, out, batch, nblocks);
}